// Round 2
// baseline (155.236 us; speedup 1.0000x reference)
//
#include <hip/hip_runtime.h>

#define HID   384
#define K_PE  768     // 3*16*16
#define IMGST 150528  // 3*224*224 floats per image
#define POS   196

typedef unsigned short ushort_t;
using f32x4  = __attribute__((ext_vector_type(4))) float;
using short8 = __attribute__((ext_vector_type(8))) short;

typedef unsigned __attribute__((address_space(1))) u32_g;
typedef unsigned __attribute__((address_space(3))) u32_s;

__device__ __forceinline__ void glds16(const void* g, void* l) {
    __builtin_amdgcn_global_load_lds((const u32_g*)g, (u32_s*)l, 16, 0, 0);
}

// ---- bf16 helpers (RNE) ----------------------------------------------------
__device__ __forceinline__ unsigned bfpack(float lo, float hi) {
    union { float f; unsigned u; } a, b; a.f = lo; b.f = hi;
    unsigned ra = (a.u + 0x7fffu + ((a.u >> 16) & 1u)) >> 16;
    unsigned rb = (b.u + 0x7fffu + ((b.u >> 16) & 1u)) & 0xffff0000u;
    return ra | rb;
}

// ---------------- pack: im2col transpose (contiguous HBM both sides) --------
// blocks 0..895: (pi, img). Read band [3][16][224] f32 contiguously, bf16 into
// LDS, write im2col[p][kbi][img][oct*16B] in 128-B pieces (64 same-pi blocks
// fill each 8-KB slab together -> full-line writes).
// blocks 896..1039: W swizzle into B-frag order + zero scal/pcnt/Lp/Qp.
__global__ __launch_bounds__(256) void pack(
    const float* __restrict__ x, const float* __restrict__ y,
    const float* __restrict__ W, ushort_t* __restrict__ Wfrag,
    ushort_t* __restrict__ imx, ushort_t* __restrict__ imy,
    float* __restrict__ scal, int* __restrict__ pcnt,
    float* __restrict__ Lp, float* __restrict__ Qp) {
    const int b   = blockIdx.x;
    const int tid = threadIdx.x;

    if (b >= 896) {            // ---- W-prep + workspace zeroing ----
        const int t = (b - 896) * 256 + tid;   // 0..36863
        if (t < 16)  scal[t] = 0.f;            // T, S, pad, done-counter
        if (t < POS) pcnt[t] = 0;
        for (int i = t; i < POS * HID; i += 36864) { Lp[i] = 0.f; Qp[i] = 0.f; }
        const int n  = t / 96;                 // 0..383
        const int ko = t - n * 96;             // k-octet
        const float4 a  = *(const float4*)(W + (size_t)n * K_PE + ko * 8);
        const float4 bb = *(const float4*)(W + (size_t)n * K_PE + ko * 8 + 4);
        uint4 pq;
        pq.x = bfpack(a.x, a.y);  pq.y = bfpack(a.z, a.w);
        pq.z = bfpack(bb.x, bb.y); pq.w = bfpack(bb.z, bb.w);
        const int nt    = n >> 4;
        const int kc    = ko >> 2;
        const int lanew = (ko & 3) * 16 + (n & 15);
        ((uint4*)Wfrag)[(nt * 24 + kc) * 64 + lanew] = pq;
        return;
    }

    const int pi  = b >> 6;    // 0..13
    const int img = b & 63;    // 0..63
    // padded LDS: row stride 232 ushorts breaks the 896-B-period bank pattern
    __shared__ __align__(16) ushort_t L[2][48 * 232];

    const float* bx = x + (size_t)img * IMGST + pi * 3584;
    const float* by = y + (size_t)img * IMGST + pi * 3584;

    // phase 1: contiguous read, bf16 convert, LDS (source layout)
    for (int i = tid; i < 2688; i += 256) {          // 48 rows x 56 float4
        const int row = i / 56;                      // c*16 + r
        const int c4  = i - row * 56;
        const int c   = row >> 4, r = row & 15;
        const size_t so = (size_t)c * 50176 + r * 224 + c4 * 4;
        const float4 fx = *(const float4*)(bx + so);
        const float4 fy = *(const float4*)(by + so);
        uint2 px, py;
        px.x = bfpack(fx.x, fx.y); px.y = bfpack(fx.z, fx.w);
        py.x = bfpack(fy.x, fy.y); py.y = bfpack(fy.z, fy.w);
        *(uint2*)&L[0][row * 232 + c4 * 4] = px;
        *(uint2*)&L[1][row * 232 + c4 * 4] = py;
    }
    __syncthreads();

    // phase 2: k-major gather from LDS, 16-B aligned writes to im2col
    for (int u = tid; u < 1344; u += 256) {          // 14 pj x 96 octs
        const int pj  = u / 96;
        const int oc  = u - pj * 96;
        const int kbi = oc >> 3, o = oc & 7;
        const int k0  = oc * 8;
        const int c   = k0 >> 8, kh = (k0 >> 4) & 15, kw0 = k0 & 15;
        const int loff = (c * 16 + kh) * 232 + pj * 16 + kw0;   // 16-B aligned
        const uint4 vx = *(const uint4*)&L[0][loff];
        const uint4 vy = *(const uint4*)&L[1][loff];
        const size_t d = ((size_t)((pi * 14 + pj) * 12 + kbi) * 64 + img) * 64 + o * 8;
        *(uint4*)&imx[d] = vx;
        *(uint4*)&imy[d] = vy;
    }
}

// ---------------- fused GEMM + softmax + full reduction ----------------------
// grid 392 = 196 positions x 2 image-halves (M=32). block 256 = 4 n-waves.
// A staged via global_load_lds (bf16, pre-swizzled source, linear LDS dest).
// Per wave: 2 mi x 6 ni frags x 2 tensors (96 acc VGPRs), 48 MFMA/K-step.
// Epilogue: fused softmax; T -> atomicAdd; col sums -> atomicAdd Lp/Qp;
// 2nd block per position computes S_p; 392nd block writes out.
__global__ __launch_bounds__(256, 3) void pe2(
    const ushort_t* __restrict__ imx, const ushort_t* __restrict__ imy,
    const ushort_t* __restrict__ Wfrag, const float* __restrict__ bias,
    float* __restrict__ scal, int* __restrict__ pcnt,
    float* __restrict__ Lp, float* __restrict__ Qp, float* __restrict__ out) {
    const int blk  = blockIdx.x;       // 0..391
    const int p    = blk >> 1;
    const int half = blk & 1;

    __shared__ __align__(16) ushort_t As[2][4096];  // [buf][x:0..2047 | y:2048..4095]
    __shared__ float Smx[4][32], Ssx[4][32], Smy[4][32], Ssy[4][32];
    __shared__ float sT[4];
    __shared__ int lastp;

    const int tid  = threadIdx.x;
    const int wave = tid >> 6;         // n-wave: cols wave*96..+96
    const int lane = tid & 63;
    const int lm   = lane & 15;
    const int lq   = lane >> 4;

    // ---- stage source (per-lane): wave w covers imgs w*8..w*8+7, swizzled oct
    const int simg = wave * 8 + (lane >> 3);            // img_local
    const int so   = (lane & 7) ^ ((lane >> 3) & 7);    // logical oct at this slot
    const size_t sbyte = (size_t)p * 98304 +
                         ((size_t)(half * 32 + simg)) * 128 + so * 16;
    const char* gx = (const char*)imx + sbyte;
    const char* gy = (const char*)imy + sbyte;

    // ---- frag read offsets: As[img*64 + ((ks*4+lq)^(lm&7))*8] (+mi*1024)
    int ard[2][2];
#pragma unroll
    for (int ks = 0; ks < 2; ++ks)
#pragma unroll
        for (int mi = 0; mi < 2; ++mi)
            ard[ks][mi] = (mi * 16 + lm) * 64 + (((ks * 4 + lq) ^ (lm & 7)) * 8);

    const ushort_t* bbase = Wfrag + (size_t)lane * 8;

    f32x4 accx[2][6] = {};
    f32x4 accy[2][6] = {};

#define STAGE(KB, BUF)                                       \
    {                                                        \
        glds16(gx + (size_t)(KB) * 8192, &As[BUF][wave * 512]);        \
        glds16(gy + (size_t)(KB) * 8192, &As[BUF][2048 + wave * 512]); \
    }

    STAGE(0, 0)
    __syncthreads();

    for (int kbi = 0; kbi < 12; ++kbi) {
        const int cur = kbi & 1;
#pragma unroll
        for (int ks = 0; ks < 2; ++ks) {
            short8 bfr[6];
#pragma unroll
            for (int ni = 0; ni < 6; ++ni)
                bfr[ni] = *(const short8*)(bbase +
                          (size_t)(((wave * 6 + ni) * 24 + kbi * 2 + ks) * 64) * 8);
            if (ks == 0 && kbi < 11) STAGE(kbi + 1, cur ^ 1)
            short8 afx[2], afy[2];
#pragma unroll
            for (int mi = 0; mi < 2; ++mi) {
                afx[mi] = *(const short8*)&As[cur][ard[ks][mi]];
                afy[mi] = *(const short8*)&As[cur][2048 + ard[ks][mi]];
            }
#pragma unroll
            for (int mi = 0; mi < 2; ++mi)
#pragma unroll
                for (int ni = 0; ni < 6; ++ni) {
                    accx[mi][ni] = __builtin_amdgcn_mfma_f32_16x16x32_bf16(
                        afx[mi], bfr[ni], accx[mi][ni], 0, 0, 0);
                    accy[mi][ni] = __builtin_amdgcn_mfma_f32_16x16x32_bf16(
                        afy[mi], bfr[ni], accy[mi][ni], 0, 0, 0);
                }
        }
        __syncthreads();
    }
#undef STAGE

    // ---- epilogue: D col = wave*96 + ni*16 + lm; row = mi*16 + lq*4 + r
#pragma unroll
    for (int ni = 0; ni < 6; ++ni) {
        const float bv = bias[wave * 96 + ni * 16 + lm];
#pragma unroll
        for (int mi = 0; mi < 2; ++mi)
#pragma unroll
            for (int r = 0; r < 4; ++r) {
                accx[mi][ni][r] += bv;
                accy[mi][ni][r] += bv;
            }
    }

    float mx[2][4], my_[2][4];
#pragma unroll
    for (int mi = 0; mi < 2; ++mi)
#pragma unroll
        for (int r = 0; r < 4; ++r) {
            float a = accx[mi][0][r], bb = accy[mi][0][r];
#pragma unroll
            for (int ni = 1; ni < 6; ++ni) {
                a  = fmaxf(a,  accx[mi][ni][r]);
                bb = fmaxf(bb, accy[mi][ni][r]);
            }
            mx[mi][r] = a; my_[mi][r] = bb;
        }
#pragma unroll
    for (int off = 1; off < 16; off <<= 1)
#pragma unroll
        for (int mi = 0; mi < 2; ++mi)
#pragma unroll
            for (int r = 0; r < 4; ++r) {
                mx[mi][r]  = fmaxf(mx[mi][r],  __shfl_xor(mx[mi][r],  off));
                my_[mi][r] = fmaxf(my_[mi][r], __shfl_xor(my_[mi][r], off));
            }
    if (lm == 0)
#pragma unroll
        for (int mi = 0; mi < 2; ++mi)
#pragma unroll
            for (int r = 0; r < 4; ++r) {
                Smx[wave][mi * 16 + lq * 4 + r] = mx[mi][r];
                Smy[wave][mi * 16 + lq * 4 + r] = my_[mi][r];
            }
    __syncthreads();
#pragma unroll
    for (int mi = 0; mi < 2; ++mi)
#pragma unroll
        for (int r = 0; r < 4; ++r) {
            const int row = mi * 16 + lq * 4 + r;
            mx[mi][r]  = fmaxf(fmaxf(Smx[0][row], Smx[1][row]),
                               fmaxf(Smx[2][row], Smx[3][row]));
            my_[mi][r] = fmaxf(fmaxf(Smy[0][row], Smy[1][row]),
                               fmaxf(Smy[2][row], Smy[3][row]));
        }

    float sx[2][4], sy[2][4];
#pragma unroll
    for (int mi = 0; mi < 2; ++mi)
#pragma unroll
        for (int r = 0; r < 4; ++r) {
            float a = 0.f, bb = 0.f;
#pragma unroll
            for (int ni = 0; ni < 6; ++ni) {
                a  += __expf(accx[mi][ni][r] - mx[mi][r]);
                bb += __expf(accy[mi][ni][r] - my_[mi][r]);
            }
            sx[mi][r] = a; sy[mi][r] = bb;
        }
#pragma unroll
    for (int off = 1; off < 16; off <<= 1)
#pragma unroll
        for (int mi = 0; mi < 2; ++mi)
#pragma unroll
            for (int r = 0; r < 4; ++r) {
                sx[mi][r] += __shfl_xor(sx[mi][r], off);
                sy[mi][r] += __shfl_xor(sy[mi][r], off);
            }
    if (lm == 0)
#pragma unroll
        for (int mi = 0; mi < 2; ++mi)
#pragma unroll
            for (int r = 0; r < 4; ++r) {
                Ssx[wave][mi * 16 + lq * 4 + r] = sx[mi][r];
                Ssy[wave][mi * 16 + lq * 4 + r] = sy[mi][r];
            }
    __syncthreads();
    float shx[2][4], invy[2][4];
#pragma unroll
    for (int mi = 0; mi < 2; ++mi)
#pragma unroll
        for (int r = 0; r < 4; ++r) {
            const int row = mi * 16 + lq * 4 + r;
            const float ssx = Ssx[0][row] + Ssx[1][row] + Ssx[2][row] + Ssx[3][row];
            const float ssy = Ssy[0][row] + Ssy[1][row] + Ssy[2][row] + Ssy[3][row];
            shx[mi][r]  = mx[mi][r] + __logf(ssx);   // logp shift
            invy[mi][r] = 1.f / ssy;                 // q scale
        }

    // T partial + per-column sums over this block's 32 rows
    float T = 0.f;
    float cL[6], cQ[6];
#pragma unroll
    for (int ni = 0; ni < 6; ++ni) { cL[ni] = 0.f; cQ[ni] = 0.f; }
#pragma unroll
    for (int mi = 0; mi < 2; ++mi)
#pragma unroll
        for (int r = 0; r < 4; ++r) {
            const float sh  = shx[mi][r];
            const float m   = my_[mi][r];
            const float inv = invy[mi][r];
#pragma unroll
            for (int ni = 0; ni < 6; ++ni) {
                const float lp = accx[mi][ni][r] - sh;
                const float qv = __expf(accy[mi][ni][r] - m) * inv;
                T += lp * qv;
                cL[ni] += lp;
                cQ[ni] += qv;
            }
        }
#pragma unroll
    for (int ni = 0; ni < 6; ++ni) {
        cL[ni] += __shfl_xor(cL[ni], 16); cL[ni] += __shfl_xor(cL[ni], 32);
        cQ[ni] += __shfl_xor(cQ[ni], 16); cQ[ni] += __shfl_xor(cQ[ni], 32);
    }
    if (lq == 0)
#pragma unroll
        for (int ni = 0; ni < 6; ++ni) {
            atomicAdd(&Lp[p * HID + wave * 96 + ni * 16 + lm], cL[ni]);
            atomicAdd(&Qp[p * HID + wave * 96 + ni * 16 + lm], cQ[ni]);
        }
#pragma unroll
    for (int off = 32; off > 0; off >>= 1) T += __shfl_xor(T, off);
    if (lane == 0) sT[wave] = T;
    __syncthreads();
    if (tid == 0) {
        atomicAdd(&scal[0], sT[0] + sT[1] + sT[2] + sT[3]);
        __threadfence();
        const int old = atomicAdd(&pcnt[p], 1);
        lastp = (old == 1);
    }
    __syncthreads();

    if (lastp) {   // 2nd block of this position: S_p = sum_c L*Q
        float s = 0.f;
        for (int c = tid; c < HID; c += 256) {
            const float Lv = atomicAdd(&Lp[p * HID + c], 0.f);
            const float Qv = atomicAdd(&Qp[p * HID + c], 0.f);
            s += Lv * Qv;
        }
#pragma unroll
        for (int off = 32; off > 0; off >>= 1) s += __shfl_xor(s, off);
        if (lane == 0) sT[wave] = s;
        __syncthreads();
        if (tid == 0) atomicAdd(&scal[1], sT[0] + sT[1] + sT[2] + sT[3]);
    }

    if (tid == 0) {
        __threadfence();
        const int g = atomicAdd((int*)&scal[3], 1);
        if (g == (int)gridDim.x - 1) {
            const float Tt = atomicAdd(&scal[0], 0.f);   // coherent read-back
            const float St = atomicAdd(&scal[1], 0.f);
            out[0] = 63.f * Tt / (St - Tt);
        }
    }
}

extern "C" void kernel_launch(void* const* d_in, const int* in_sizes, int n_in,
                              void* d_out, int out_size, void* d_ws, size_t ws_size,
                              hipStream_t stream) {
    const float* x = (const float*)d_in[0];   // (64,3,224,224)
    const float* y = (const float*)d_in[1];   // (64,3,224,224)
    const float* W = (const float*)d_in[2];   // (384,768)
    const float* b = (const float*)d_in[3];   // (384,)
    float* out = (float*)d_out;

    char* ws = (char*)d_ws;
    float*    scal  = (float*)ws;                      // 1 KB
    int*      pcnt  = (int*)(ws + 1024);               // 196 ints
    ushort_t* Wfrag = (ushort_t*)(ws + 2048);          // 589,824 B
    float*    Lp    = (float*)(ws + 591872);           // 301,056 B
    float*    Qp    = (float*)(ws + 892928);           // 301,056 B
    ushort_t* imx   = (ushort_t*)(ws + 1196032);       // 19,267,584 B
    ushort_t* imy   = (ushort_t*)(ws + 20463616);      // 19,267,584 B

    pack<<<1040, 256, 0, stream>>>(x, y, W, Wfrag, imx, imy, scal, pcnt, Lp, Qp);
    pe2<<<392, 256, 0, stream>>>(imx, imy, Wfrag, b, scal, pcnt, Lp, Qp, out);
}